// Round 1
// baseline (808.654 us; speedup 1.0000x reference)
//
#include <hip/hip_runtime.h>
#include <hip/hip_bf16.h>
#include <math.h>

// Problem constants (fixed by reference)
#define BN_ROWS   8192            // B*N
#define MO_       32
#define D_        256
#define NQ_       64              // 2*MO
#define NL_       2048            // MO*2*MO
#define ROW_F32   8192            // MO*D floats per output row region
#define ROW_BYTES 32768
#define H_OFF_B   4096            // byte offset of h slot inside row region
#define OUT_BUF_ELEMS 67108864    // BN_ROWS * ROW_F32

typedef __bf16 bf16x8 __attribute__((ext_vector_type(8)));
typedef float  floatx4 __attribute__((ext_vector_type(4)));

__device__ __forceinline__ float gelu_exact(float x) {
    return 0.5f * x * (1.0f + erff(x * 0.70710678118654752f));
}

// ---------------------------------------------------------------------------
// K1a: feats -> layer1 (VALU) -> layer2 (MFMA bf16) -> h stored bf16 into
//      d_out row regions at byte offset 4096.
// grid = 128 row-strips x 4 col-strips = 512 blocks, 256 threads.
// ---------------------------------------------------------------------------
__global__ __launch_bounds__(256) void k_mlp12(
    const float* __restrict__ lcount, const float* __restrict__ rcount,
    const int* __restrict__ subs, const float* __restrict__ W1,
    const float* __restrict__ b1, const float* __restrict__ W2,
    const float* __restrict__ b2, float* __restrict__ out)
{
    const int mstrip = blockIdx.x >> 2;   // 0..127
    const int nstrip = blockIdx.x & 3;    // 0..3  (64 cols of h each)
    const int m0 = mstrip * 64;
    const int tid = threadIdx.x;

    __shared__ __attribute__((aligned(16))) float feats[64][4];
    __shared__ __attribute__((aligned(16))) __bf16 h1[64][264]; // +8 pad

    if (tid < 64) {
        int row = m0 + tid;
        float lc = lcount[row] * (1.0f / 32.0f);
        float rc = rcount[row] * (1.0f / 32.0f);
        int s = subs[row];
        s = s < 0 ? 0 : (s > 1 ? 1 : s);
        feats[tid][0] = lc;
        feats[tid][1] = rc;
        feats[tid][2] = (s == 0) ? 1.0f : 0.0f;
        feats[tid][3] = (s == 1) ? 1.0f : 0.0f;
    }
    __syncthreads();

    // layer 1: thread t computes column t of h1 for all 64 rows (4 MACs each)
    {
        const float4 w = reinterpret_cast<const float4*>(W1)[tid];
        const float bb = b1[tid];
        #pragma unroll 8
        for (int r = 0; r < 64; ++r) {
            const float4 f = *reinterpret_cast<const float4*>(&feats[r][0]);
            float x = bb + f.x * w.x + f.y * w.y + f.z * w.z + f.w * w.w;
            h1[r][tid] = (__bf16)gelu_exact(x);
        }
    }
    __syncthreads();

    // layer 2 as MFMA: C[64 rows][64 cols strip] = h1 @ W2^T
    const int wave = tid >> 6;
    const int lane = tid & 63;
    const int l15  = lane & 15;
    const int quad = lane >> 4;

    floatx4 acc[4];
    #pragma unroll
    for (int t = 0; t < 4; ++t) acc[t] = 0.0f;

    #pragma unroll
    for (int k0 = 0; k0 < 256; k0 += 32) {
        const bf16x8 af = *reinterpret_cast<const bf16x8*>(&h1[wave * 16 + l15][k0 + quad * 8]);
        #pragma unroll
        for (int t = 0; t < 4; ++t) {
            const int n = nstrip * 64 + t * 16 + l15;
            const float* wrow = W2 + (size_t)n * 256 + k0 + quad * 8;
            const float4 v0 = *reinterpret_cast<const float4*>(wrow);
            const float4 v1 = *reinterpret_cast<const float4*>(wrow + 4);
            bf16x8 bf;
            bf[0] = (__bf16)v0.x; bf[1] = (__bf16)v0.y; bf[2] = (__bf16)v0.z; bf[3] = (__bf16)v0.w;
            bf[4] = (__bf16)v1.x; bf[5] = (__bf16)v1.y; bf[6] = (__bf16)v1.z; bf[7] = (__bf16)v1.w;
            acc[t] = __builtin_amdgcn_mfma_f32_16x16x32_bf16(af, bf, acc[t], 0, 0, 0);
        }
    }

    // epilogue: +b2, gelu, store bf16 h into per-row slot
    #pragma unroll
    for (int t = 0; t < 4; ++t) {
        const int n = nstrip * 64 + t * 16 + l15;
        const float bb = b2[n];
        #pragma unroll
        for (int i = 0; i < 4; ++i) {
            const int row = m0 + wave * 16 + quad * 4 + i;
            float v = gelu_exact(acc[t][i] + bb);
            __bf16* hp = (__bf16*)((char*)out + (size_t)row * ROW_BYTES + H_OFF_B);
            hp[n] = (__bf16)v;
        }
    }
}

// ---------------------------------------------------------------------------
// K1b: logits = h @ W3^T + b3, softmax over q (64), store attn bf16 into
//      d_out row regions at byte offset 0.
// grid = 128 row-strips x 32 p-strips = 4096 blocks, 256 threads. No LDS.
// ---------------------------------------------------------------------------
__global__ __launch_bounds__(256) void k_mlp3_softmax(
    const float* __restrict__ W3, const float* __restrict__ b3,
    float* out)
{
    const int mstrip = blockIdx.x >> 5;   // 0..127
    const int p      = blockIdx.x & 31;   // 0..31
    const int m0 = mstrip * 64;
    const int tid  = threadIdx.x;
    const int wave = tid >> 6;
    const int lane = tid & 63;
    const int l15  = lane & 15;
    const int quad = lane >> 4;

    floatx4 acc[4];
    #pragma unroll
    for (int t = 0; t < 4; ++t) acc[t] = 0.0f;

    #pragma unroll
    for (int k0 = 0; k0 < 256; k0 += 32) {
        const int arow = m0 + wave * 16 + l15;
        const bf16x8 af = *reinterpret_cast<const bf16x8*>(
            (const char*)out + (size_t)arow * ROW_BYTES + H_OFF_B + (size_t)(k0 + quad * 8) * 2);
        #pragma unroll
        for (int t = 0; t < 4; ++t) {
            const int n = p * 64 + t * 16 + l15;
            const float* wrow = W3 + (size_t)n * 256 + k0 + quad * 8;
            const float4 v0 = *reinterpret_cast<const float4*>(wrow);
            const float4 v1 = *reinterpret_cast<const float4*>(wrow + 4);
            bf16x8 bf;
            bf[0] = (__bf16)v0.x; bf[1] = (__bf16)v0.y; bf[2] = (__bf16)v0.z; bf[3] = (__bf16)v0.w;
            bf[4] = (__bf16)v1.x; bf[5] = (__bf16)v1.y; bf[6] = (__bf16)v1.z; bf[7] = (__bf16)v1.w;
            acc[t] = __builtin_amdgcn_mfma_f32_16x16x32_bf16(af, bf, acc[t], 0, 0, 0);
        }
    }

    // +b3; softmax over the 64 q columns per row. Row r=quad*4+i lives in the
    // 16 lanes of this quad (cols t*16 + l15).
    float vals[4][4];
    #pragma unroll
    for (int t = 0; t < 4; ++t) {
        const float bb = b3[p * 64 + t * 16 + l15];
        #pragma unroll
        for (int i = 0; i < 4; ++i) vals[t][i] = acc[t][i] + bb;
    }
    float mx[4], sm[4];
    #pragma unroll
    for (int i = 0; i < 4; ++i) {
        mx[i] = fmaxf(fmaxf(vals[0][i], vals[1][i]), fmaxf(vals[2][i], vals[3][i]));
    }
    #pragma unroll
    for (int d = 1; d < 16; d <<= 1) {
        #pragma unroll
        for (int i = 0; i < 4; ++i) mx[i] = fmaxf(mx[i], __shfl_xor(mx[i], d));
    }
    #pragma unroll
    for (int t = 0; t < 4; ++t)
        #pragma unroll
        for (int i = 0; i < 4; ++i) vals[t][i] = __expf(vals[t][i] - mx[i]);
    #pragma unroll
    for (int i = 0; i < 4; ++i)
        sm[i] = vals[0][i] + vals[1][i] + vals[2][i] + vals[3][i];
    #pragma unroll
    for (int d = 1; d < 16; d <<= 1) {
        #pragma unroll
        for (int i = 0; i < 4; ++i) sm[i] += __shfl_xor(sm[i], d);
    }
    float inv[4];
    #pragma unroll
    for (int i = 0; i < 4; ++i) inv[i] = 1.0f / sm[i];

    #pragma unroll
    for (int i = 0; i < 4; ++i) {
        const int row = m0 + wave * 16 + quad * 4 + i;
        __bf16* ap = (__bf16*)((char*)out + (size_t)row * ROW_BYTES);
        #pragma unroll
        for (int t = 0; t < 4; ++t) {
            ap[p * 64 + t * 16 + l15] = (__bf16)(vals[t][i] * inv[i]);
        }
    }
}

// ---------------------------------------------------------------------------
// K2: per-row einsum  out[p][d] = sum_q attn[p][q] * concat[q][d], plus
//     new_count. One block per row; thread t owns column d=t.
// ---------------------------------------------------------------------------
__global__ __launch_bounds__(256) void k_einsum(
    const float* __restrict__ left, const float* __restrict__ right,
    const float* __restrict__ lcount, const float* __restrict__ rcount,
    float* out)
{
    const int row = blockIdx.x;
    const int tid = threadIdx.x;

    __shared__ __attribute__((aligned(16))) float attnf[2048];

    // stage attn (bf16 -> f32) into LDS
    {
        const __bf16* ab = (const __bf16*)((const char*)out + (size_t)row * ROW_BYTES);
        const bf16x8 v = *reinterpret_cast<const bf16x8*>(ab + tid * 8);
        float4 f0, f1;
        f0.x = (float)v[0]; f0.y = (float)v[1]; f0.z = (float)v[2]; f0.w = (float)v[3];
        f1.x = (float)v[4]; f1.y = (float)v[5]; f1.z = (float)v[6]; f1.w = (float)v[7];
        reinterpret_cast<float4*>(attnf)[tid * 2 + 0] = f0;
        reinterpret_cast<float4*>(attnf)[tid * 2 + 1] = f1;
    }
    __syncthreads();

    // load my column of concat = [left row (32); right row (32)]
    float c[64];
    {
        const float* lp = left  + (size_t)row * ROW_F32 + tid;
        const float* rp = right + (size_t)row * ROW_F32 + tid;
        #pragma unroll
        for (int q = 0; q < 32; ++q) c[q]      = lp[q * 256];
        #pragma unroll
        for (int q = 0; q < 32; ++q) c[32 + q] = rp[q * 256];
    }

    #pragma unroll 2
    for (int pp = 0; pp < 32; ++pp) {
        float acc = 0.0f;
        const float4* a4 = reinterpret_cast<const float4*>(&attnf[pp * 64]);
        #pragma unroll
        for (int q4 = 0; q4 < 16; ++q4) {
            const float4 a = a4[q4];
            acc += a.x * c[q4 * 4 + 0];
            acc += a.y * c[q4 * 4 + 1];
            acc += a.z * c[q4 * 4 + 2];
            acc += a.w * c[q4 * 4 + 3];
        }
        out[(size_t)row * ROW_F32 + pp * 256 + tid] = acc;
    }

    if (tid == 0) {
        out[OUT_BUF_ELEMS + row] = fminf(lcount[row] + rcount[row], 32.0f);
    }
}

// ---------------------------------------------------------------------------
extern "C" void kernel_launch(void* const* d_in, const int* in_sizes, int n_in,
                              void* d_out, int out_size, void* d_ws, size_t ws_size,
                              hipStream_t stream)
{
    const float* left   = (const float*)d_in[0];
    const float* lcount = (const float*)d_in[1];
    const float* right  = (const float*)d_in[2];
    const float* rcount = (const float*)d_in[3];
    const int*   subs   = (const int*)  d_in[4];
    const float* W1     = (const float*)d_in[5];
    const float* b1     = (const float*)d_in[6];
    const float* W2     = (const float*)d_in[7];
    const float* b2     = (const float*)d_in[8];
    const float* W3     = (const float*)d_in[9];
    const float* b3     = (const float*)d_in[10];
    float* out = (float*)d_out;

    hipLaunchKernelGGL(k_mlp12, dim3(512), dim3(256), 0, stream,
                       lcount, rcount, subs, W1, b1, W2, b2, out);
    hipLaunchKernelGGL(k_mlp3_softmax, dim3(4096), dim3(256), 0, stream,
                       W3, b3, out);
    hipLaunchKernelGGL(k_einsum, dim3(8192), dim3(256), 0, stream,
                       left, right, lcount, rcount, out);
}